// Round 7
// baseline (1052.483 us; speedup 1.0000x reference)
//
#include <hip/hip_runtime.h>

#define T_ 30
#define H_ 41
#define WD_ 2048
#define NSEC 9
#define FM 50
#define WP 502
#define THRESH 23.0f
#define POOLED_SIZE (NSEC * T_ * FM * WP)   // 6,777,000
#define MARGIN 0.0078125f                   // 2^-7 >= worst-case split error
#define NFRAG 18432                         // 9 sec * 64 fm * 32 tap-octets

typedef short short8 __attribute__((ext_vector_type(8)));
typedef short short4v __attribute__((ext_vector_type(4)));
typedef float f32x4 __attribute__((ext_vector_type(4)));

__device__ __forceinline__ unsigned bf16_rne(float f) {
    unsigned u = __float_as_uint(f);
    return (u + 0x7fffu + ((u >> 16) & 1u)) >> 16;
}

// ---------------- prep: W -> MFMA-ready bf16 hi/lo fragments in ws --------
// frag gid = (sec*64 + fm)*32 + blk, taps t0=8*blk..+7, pairs packed low=even.
// Also initializes the 9 argmin keys (merged init_kernel).
__global__ __launch_bounds__(256) void prep_kernel(
    const float* __restrict__ Wg, int* __restrict__ wsi,
    uint4* __restrict__ wfh, uint4* __restrict__ wfl)
{
    const int gid = blockIdx.x * 256 + threadIdx.x;
    if (gid < NSEC) wsi[gid] = 0x7fffffff;
    if (gid >= NFRAG) return;
    const int blk = gid & 31;
    const int fm  = (gid >> 5) & 63;
    const int sec = gid >> 11;
    const int t0  = blk * 8;
    const bool valid = (t0 < 240) && (fm < FM);
    unsigned hh[4], ll[4];
    const float* wp = Wg + ((size_t)sec * FM + (valid ? fm : 0)) * 240 + (valid ? t0 : 0);
    float4 wa = *reinterpret_cast<const float4*>(wp);
    float4 wb = *reinterpret_cast<const float4*>(wp + 4);
    float f[8] = {wa.x, wa.y, wa.z, wa.w, wb.x, wb.y, wb.z, wb.w};
#pragma unroll
    for (int i = 0; i < 4; ++i) {
        float f0 = valid ? f[2 * i] : 0.f;
        float f1 = valid ? f[2 * i + 1] : 0.f;
        unsigned h0 = bf16_rne(f0), h1 = bf16_rne(f1);
        float hf0 = __uint_as_float(h0 << 16), hf1 = __uint_as_float(h1 << 16);
        unsigned l0 = bf16_rne(f0 - hf0), l1 = bf16_rne(f1 - hf1);
        hh[i] = (h1 << 16) | h0;
        ll[i] = (l1 << 16) | l0;
    }
    wfh[gid] = *reinterpret_cast<uint4*>(hh);
    wfl[gid] = *reinterpret_cast<uint4*>(ll);
}

// ---------------- Kernel A: split-bf16 MFMA conv + fire + 4x4 pool ---------
// Same verified geometry as R6 (C[m=pot][n=fm] 16x16x32, m strides pot cols
// by 8, res 0..7, wave = pot row j_p). R7: x in LDS as SEPARATE hi/lo u16
// arrays (4 shifted copies) -> res<4 reads are ds_read_b128, res>=4 are
// 2x ds_read_b64, NO repack bitops (was ~6k VALU/wave). W frags prebuilt
// in ws by prep_kernel (was ~3.2k VALU/wave of cvt/pack per wave).
template <bool PRE>
__global__ __launch_bounds__(256) void conv_pool_kernel(
    const float* __restrict__ x, const float* __restrict__ Wg,
    const uint4* __restrict__ wfh, const uint4* __restrict__ wfl,
    float* __restrict__ out)
{
    __shared__ __align__(16) unsigned short xh[4][10][176];   // 13.75 KB
    __shared__ __align__(16) unsigned short xl[4][10][176];   // 13.75 KB
    __shared__ unsigned lmask[4][64];

    const int b       = blockIdx.x;
    const int coltile = b & 15;
    const int tt      = (b >> 4) % T_;
    const int sec     = b / 480;
    const int w0      = coltile * 128;     // pot-col base
    const int rowbase = 4 * sec;
    const int tid     = threadIdx.x;

    // ---- stage x: 10 rows x 176 cols -> hi/lo u16, 4 shifted copies ----
    for (int i = tid; i < 440; i += 256) {
        const int row = i / 44;
        const int c4  = i % 44;
        const int grow = (rowbase + row < H_) ? rowbase + row : H_ - 1;
        const int gc   = w0 + 4 * c4;
        float4 v;
        if (gc + 3 < WD_) {
            v = *reinterpret_cast<const float4*>(x + ((size_t)tt * H_ + grow) * WD_ + gc);
        } else {
            v.x = v.y = v.z = v.w = 0.f;
        }
        float f[4] = {v.x, v.y, v.z, v.w};
        unsigned short hq[4], lq[4];
#pragma unroll
        for (int e = 0; e < 4; ++e) {
            unsigned h = bf16_rne(f[e]);
            float hf = __uint_as_float(h << 16);
            unsigned l = bf16_rne(f[e] - hf);
            hq[e] = (unsigned short)h;
            lq[e] = (unsigned short)l;
        }
#pragma unroll
        for (int S = 0; S < 4; ++S)
#pragma unroll
            for (int e = 0; e < 4; ++e) {
                const int j = 4 * c4 + e - S;
                if (j >= 0 && j < 176) { xh[S][row][j] = hq[e]; xl[S][row][j] = lq[e]; }
            }
    }
    __syncthreads();

    const int L    = tid & 63;
    const int j_p  = tid >> 6;       // wave id = pot row
    const int q    = L >> 4;         // quad
    const int n16  = L & 15;         // A: m-index; B: fm-index

    // per-kk tap geometry (tau0 = 32kk + 8q -> weight row r, col c0)
    int preidx[8];                   // u16-element index into a shift plane
    int tau0s[8];
#pragma unroll
    for (int kk = 0; kk < 8; ++kk) {
        const int t0 = 32 * kk + 8 * q;
        const int r  = t0 / 40;
        const int c0 = t0 - 40 * r;
        tau0s[kk]  = t0;
        preidx[kk] = (j_p + r) * 176 + c0 + 8 * n16;
    }

    unsigned mask = 0;

#pragma unroll 1
    for (int ft = 0; ft < 4; ++ft) {
        const int fm = ft * 16 + n16;
        short8 wh[8], wl[8];
        if (PRE) {
            const int fb = (sec * 64 + ft * 16 + n16) * 32 + q;
#pragma unroll
            for (int kk = 0; kk < 8; ++kk) {
                uint4 hu = wfh[fb + 4 * kk];
                uint4 lu = wfl[fb + 4 * kk];
                union { uint4 u; short8 s; } c1, c2;
                c1.u = hu; c2.u = lu;
                wh[kk] = c1.s; wl[kk] = c2.s;
            }
        } else {
            // fallback: in-kernel build (R6 path, used only if ws too small)
#pragma unroll
            for (int kk = 0; kk < 8; ++kk) {
                const int t0 = tau0s[kk];
                const bool wvalid = (t0 < 240) && (fm < FM);
                const float* wp = Wg + (size_t)sec * FM * 240 +
                                  (size_t)(wvalid ? fm : 0) * 240 + (wvalid ? t0 : 0);
                float4 wa = *reinterpret_cast<const float4*>(wp);
                float4 wb = *reinterpret_cast<const float4*>(wp + 4);
                float f[8] = {wa.x, wa.y, wa.z, wa.w, wb.x, wb.y, wb.z, wb.w};
                unsigned hh[4], ll[4];
#pragma unroll
                for (int i = 0; i < 4; ++i) {
                    float f0 = wvalid ? f[2 * i] : 0.f;
                    float f1 = wvalid ? f[2 * i + 1] : 0.f;
                    unsigned h0 = bf16_rne(f0), h1 = bf16_rne(f1);
                    float hf0 = __uint_as_float(h0 << 16), hf1 = __uint_as_float(h1 << 16);
                    unsigned l0 = bf16_rne(f0 - hf0), l1 = bf16_rne(f1 - hf1);
                    hh[i] = (h1 << 16) | h0;
                    ll[i] = (l1 << 16) | l0;
                }
                wh[kk] = *reinterpret_cast<short8*>(hh);
                wl[kk] = *reinterpret_cast<short8*>(ll);
            }
        }

#pragma unroll
        for (int res = 0; res < 8; ++res) {
            const int S   = res & 3;
            const int off = (res >> 2) << 2;          // 0 or 4 cols
            const unsigned short* hb = &xh[S][0][0] + off;
            const unsigned short* lb = &xl[S][0][0] + off;

            f32x4 acc = {0.f, 0.f, 0.f, 0.f};
#pragma unroll
            for (int kk = 0; kk < 8; ++kk) {
                short8 ah, al;
                if (off == 0) {                       // 16B-aligned: b128
                    ah = *reinterpret_cast<const short8*>(hb + preidx[kk]);
                    al = *reinterpret_cast<const short8*>(lb + preidx[kk]);
                } else {                              // 8B-aligned: 2x b64
                    short4v h0 = *reinterpret_cast<const short4v*>(hb + preidx[kk]);
                    short4v h1 = *reinterpret_cast<const short4v*>(hb + preidx[kk] + 4);
                    short4v l0 = *reinterpret_cast<const short4v*>(lb + preidx[kk]);
                    short4v l1 = *reinterpret_cast<const short4v*>(lb + preidx[kk] + 4);
                    ah = __builtin_shufflevector(h0, h1, 0, 1, 2, 3, 4, 5, 6, 7);
                    al = __builtin_shufflevector(l0, l1, 0, 1, 2, 3, 4, 5, 6, 7);
                }
                acc = __builtin_amdgcn_mfma_f32_16x16x32_bf16(ah, wh[kk], acc, 0, 0, 0);
                acc = __builtin_amdgcn_mfma_f32_16x16x32_bf16(al, wh[kk], acc, 0, 0, 0);
                acc = __builtin_amdgcn_mfma_f32_16x16x32_bf16(ah, wl[kk], acc, 0, 0, 0);
            }

            // ---- epilogue: repair borderline, set pool bits ----
#pragma unroll
            for (int reg = 0; reg < 4; ++reg) {
                float v = acc[reg];
                const int m   = q * 4 + reg;
                const int pcg = w0 + res + 8 * m;     // global pot col
                const bool valid = (fm < FM) && (pcg <= 2007);
                if (valid && __builtin_fabsf(v - THRESH) < MARGIN) {
                    float pot = 0.f;
#pragma unroll 1
                    for (int r2 = 0; r2 < 6; ++r2) {
                        const float* xr = x + ((size_t)tt * H_ + rowbase + j_p + r2) * WD_ + pcg;
                        const float* wr = Wg + (size_t)sec * FM * 240 + (size_t)fm * 240 + r2 * 40;
#pragma unroll 1
                        for (int c = 0; c < 40; ++c)
                            pot = fmaf(xr[c], wr[c], pot);
                    }
                    v = pot;
                }
                if (v > THRESH)
                    mask |= 1u << (reg * 8 + ft * 2 + (res >> 2));
            }
        }
    }

    lmask[j_p][L] = mask;
    __syncthreads();

    // ---- cross-wave OR + pooled write: 64 fm x 32 pooled cols ----
    for (int e = tid; e < 2048; e += 256) {
        const int fmo = e >> 5, p = e & 31;
        const int m = p >> 1, rg = p & 1, ftc = fmo >> 4, fn = fmo & 15;
        const int lane = (m >> 2) * 16 + fn;
        const int bitpos = (m & 3) * 8 + ftc * 2 + rg;
        const unsigned bits = lmask[0][lane] | lmask[1][lane] |
                              lmask[2][lane] | lmask[3][lane];
        const int pg = coltile * 32 + p;
        if (fmo < FM && pg < WP)
            out[((size_t)(sec * T_ + tt) * FM + fmo) * WP + pg] =
                ((bits >> bitpos) & 1u) ? 1.0f : 0.0f;
    }
}

// ---------------- init (fallback only) ----------------
__global__ void init_kernel(int* __restrict__ ws)
{
    if (threadIdx.x < NSEC) ws[threadIdx.x] = 0x7fffffff;
}

// ---------------- Kernel C: first-spike scan + argmin reduce ----------------
__global__ __launch_bounds__(256) void scan_kernel(
    const float* __restrict__ pooled, int* __restrict__ ws)
{
    __shared__ int sk[256];
    const int sec = blockIdx.x / 99;
    const int bi  = blockIdx.x % 99;
    const int e   = bi * 256 + threadIdx.x;
    int key = 0x7fffffff;
    if (e < FM * WP) {
        const int fm = e / WP;
        const int wp = e % WP;
        const size_t base = ((size_t)(sec * T_) * FM + fm) * WP + wp;
        const size_t tstride = (size_t)FM * WP;
#pragma unroll 1
        for (int t = 0; t < T_; ++t) {
            if (pooled[base + t * tstride] > 0.f) { key = (t << 15) | e; break; }
        }
    }
    sk[threadIdx.x] = key;
    __syncthreads();
    for (int s = 128; s > 0; s >>= 1) {
        if (threadIdx.x < s) sk[threadIdx.x] = min(sk[threadIdx.x], sk[threadIdx.x + s]);
        __syncthreads();
    }
    if (threadIdx.x == 0) atomicMin(&ws[sec], sk[0]);
}

// ---------------- Kernel D: finalize winners ----------------
__global__ void finalize_kernel(const int* __restrict__ ws, float* __restrict__ out)
{
    const int i = threadIdx.x;
    if (i < NSEC) {
        const int key = ws[i];
        float feat;
        if (key == 0x7fffffff) feat = -1.0f;
        else                   feat = (float)((key & 32767) / WP);
        out[POOLED_SIZE + i] = feat;
    }
}

extern "C" void kernel_launch(void* const* d_in, const int* in_sizes, int n_in,
                              void* d_out, int out_size, void* d_ws, size_t ws_size,
                              hipStream_t stream) {
    const float* x  = (const float*)d_in[0];
    const float* Wg = (const float*)d_in[1];
    float* out = (float*)d_out;
    int*   wsi = (int*)d_ws;
    uint4* wfh = (uint4*)((char*)d_ws + 256);
    uint4* wfl = wfh + NFRAG;

    const bool pre = ws_size >= 256 + (size_t)NFRAG * 16 * 2;   // 590 KB
    if (pre) {
        prep_kernel<<<dim3(72), dim3(256), 0, stream>>>(Wg, wsi, wfh, wfl);
        conv_pool_kernel<true><<<dim3(4320), dim3(256), 0, stream>>>(x, Wg, wfh, wfl, out);
    } else {
        init_kernel<<<dim3(1), dim3(64), 0, stream>>>(wsi);
        conv_pool_kernel<false><<<dim3(4320), dim3(256), 0, stream>>>(x, Wg, wfh, wfl, out);
    }
    scan_kernel<<<dim3(NSEC * 99), dim3(256), 0, stream>>>(out, wsi);
    finalize_kernel<<<dim3(1), dim3(16), 0, stream>>>(wsi, out);
}

// Round 8
// 367.892 us; speedup vs baseline: 2.8608x; 2.8608x over previous
//
#include <hip/hip_runtime.h>

#define T_ 30
#define H_ 41
#define WD_ 2048
#define NSEC 9
#define FM 50
#define WP 502
#define THRESH 23.0f
#define POOLED_SIZE (NSEC * T_ * FM * WP)   // 6,777,000
#define MARGIN 0.0078125f                   // 2^-7 >= worst-case split error
#define NFRAG 18432                         // 9 sec * 64 fm * 32 tap-octets

typedef short short8 __attribute__((ext_vector_type(8)));
typedef short short4v __attribute__((ext_vector_type(4)));
typedef float f32x4 __attribute__((ext_vector_type(4)));

__device__ __forceinline__ unsigned bf16_rne(float f) {
    unsigned u = __float_as_uint(f);
    return (u + 0x7fffu + ((u >> 16) & 1u)) >> 16;
}

// ---------------- prep: W -> MFMA-ready bf16 hi/lo fragments in ws --------
// frag gid = (sec*64 + fm)*32 + blk, taps t0=8*blk..+7, pairs packed low=even.
// Also initializes the 9 argmin keys (merged init_kernel).
__global__ __launch_bounds__(256) void prep_kernel(
    const float* __restrict__ Wg, int* __restrict__ wsi,
    uint4* __restrict__ wfh, uint4* __restrict__ wfl)
{
    const int gid = blockIdx.x * 256 + threadIdx.x;
    if (gid < NSEC) wsi[gid] = 0x7fffffff;
    if (gid >= NFRAG) return;
    const int blk = gid & 31;
    const int fm  = (gid >> 5) & 63;
    const int sec = gid >> 11;
    const int t0  = blk * 8;
    const bool valid = (t0 < 240) && (fm < FM);
    unsigned hh[4], ll[4];
    const float* wp = Wg + ((size_t)sec * FM + (valid ? fm : 0)) * 240 + (valid ? t0 : 0);
    float4 wa = *reinterpret_cast<const float4*>(wp);
    float4 wb = *reinterpret_cast<const float4*>(wp + 4);
    float f[8] = {wa.x, wa.y, wa.z, wa.w, wb.x, wb.y, wb.z, wb.w};
#pragma unroll
    for (int i = 0; i < 4; ++i) {
        float f0 = valid ? f[2 * i] : 0.f;
        float f1 = valid ? f[2 * i + 1] : 0.f;
        unsigned h0 = bf16_rne(f0), h1 = bf16_rne(f1);
        float hf0 = __uint_as_float(h0 << 16), hf1 = __uint_as_float(h1 << 16);
        unsigned l0 = bf16_rne(f0 - hf0), l1 = bf16_rne(f1 - hf1);
        hh[i] = (h1 << 16) | h0;
        ll[i] = (l1 << 16) | l0;
    }
    wfh[gid] = *reinterpret_cast<uint4*>(hh);
    wfl[gid] = *reinterpret_cast<uint4*>(ll);
}

// ---------------- Kernel A: split-bf16 MFMA conv + fire + 4x4 pool ---------
// Same verified geometry as R6 (C[m=pot][n=fm] 16x16x32, m strides pot cols
// by 8, res 0..7, wave = pot row j_p). x in LDS as SEPARATE hi/lo u16 arrays
// (4 shifted copies): res<4 -> ds_read_b128, res>=4 -> 2x ds_read_b64, no
// repack bitops. W frags prebuilt in ws. res loop MUST stay `#pragma
// unroll 1`: full unroll in R7 blew VGPR to 256 + ~1 GB scratch spills.
template <bool PRE>
__global__ __launch_bounds__(256) void conv_pool_kernel(
    const float* __restrict__ x, const float* __restrict__ Wg,
    const uint4* __restrict__ wfh, const uint4* __restrict__ wfl,
    float* __restrict__ out)
{
    __shared__ __align__(16) unsigned short xh[4][10][176];   // 13.75 KB
    __shared__ __align__(16) unsigned short xl[4][10][176];   // 13.75 KB
    __shared__ unsigned lmask[4][64];

    const int b       = blockIdx.x;
    const int coltile = b & 15;
    const int tt      = (b >> 4) % T_;
    const int sec     = b / 480;
    const int w0      = coltile * 128;     // pot-col base
    const int rowbase = 4 * sec;
    const int tid     = threadIdx.x;

    // ---- stage x: 10 rows x 176 cols -> hi/lo u16, 4 shifted copies ----
    for (int i = tid; i < 440; i += 256) {
        const int row = i / 44;
        const int c4  = i % 44;
        const int grow = (rowbase + row < H_) ? rowbase + row : H_ - 1;
        const int gc   = w0 + 4 * c4;
        float4 v;
        if (gc + 3 < WD_) {
            v = *reinterpret_cast<const float4*>(x + ((size_t)tt * H_ + grow) * WD_ + gc);
        } else {
            v.x = v.y = v.z = v.w = 0.f;
        }
        float f[4] = {v.x, v.y, v.z, v.w};
        unsigned short hq[4], lq[4];
#pragma unroll
        for (int e = 0; e < 4; ++e) {
            unsigned h = bf16_rne(f[e]);
            float hf = __uint_as_float(h << 16);
            unsigned l = bf16_rne(f[e] - hf);
            hq[e] = (unsigned short)h;
            lq[e] = (unsigned short)l;
        }
#pragma unroll
        for (int S = 0; S < 4; ++S)
#pragma unroll
            for (int e = 0; e < 4; ++e) {
                const int j = 4 * c4 + e - S;
                if (j >= 0 && j < 176) { xh[S][row][j] = hq[e]; xl[S][row][j] = lq[e]; }
            }
    }
    __syncthreads();

    const int L    = tid & 63;
    const int j_p  = tid >> 6;       // wave id = pot row
    const int q    = L >> 4;         // quad
    const int n16  = L & 15;         // A: m-index; B: fm-index

    // per-kk tap geometry (tau0 = 32kk + 8q -> weight row r, col c0)
    int preidx[8];                   // u16-element index into a shift plane
    int tau0s[8];
#pragma unroll
    for (int kk = 0; kk < 8; ++kk) {
        const int t0 = 32 * kk + 8 * q;
        const int r  = t0 / 40;
        const int c0 = t0 - 40 * r;
        tau0s[kk]  = t0;
        preidx[kk] = (j_p + r) * 176 + c0 + 8 * n16;
    }

    unsigned mask = 0;

#pragma unroll 1
    for (int ft = 0; ft < 4; ++ft) {
        const int fm = ft * 16 + n16;
        short8 wh[8], wl[8];
        if (PRE) {
            const int fb = (sec * 64 + ft * 16 + n16) * 32 + q;
#pragma unroll
            for (int kk = 0; kk < 8; ++kk) {
                uint4 hu = wfh[fb + 4 * kk];
                uint4 lu = wfl[fb + 4 * kk];
                union { uint4 u; short8 s; } c1, c2;
                c1.u = hu; c2.u = lu;
                wh[kk] = c1.s; wl[kk] = c2.s;
            }
        } else {
            // fallback: in-kernel build (R6 path, used only if ws too small)
#pragma unroll
            for (int kk = 0; kk < 8; ++kk) {
                const int t0 = tau0s[kk];
                const bool wvalid = (t0 < 240) && (fm < FM);
                const float* wp = Wg + (size_t)sec * FM * 240 +
                                  (size_t)(wvalid ? fm : 0) * 240 + (wvalid ? t0 : 0);
                float4 wa = *reinterpret_cast<const float4*>(wp);
                float4 wb = *reinterpret_cast<const float4*>(wp + 4);
                float f[8] = {wa.x, wa.y, wa.z, wa.w, wb.x, wb.y, wb.z, wb.w};
                unsigned hh[4], ll[4];
#pragma unroll
                for (int i = 0; i < 4; ++i) {
                    float f0 = wvalid ? f[2 * i] : 0.f;
                    float f1 = wvalid ? f[2 * i + 1] : 0.f;
                    unsigned h0 = bf16_rne(f0), h1 = bf16_rne(f1);
                    float hf0 = __uint_as_float(h0 << 16), hf1 = __uint_as_float(h1 << 16);
                    unsigned l0 = bf16_rne(f0 - hf0), l1 = bf16_rne(f1 - hf1);
                    hh[i] = (h1 << 16) | h0;
                    ll[i] = (l1 << 16) | l0;
                }
                wh[kk] = *reinterpret_cast<short8*>(hh);
                wl[kk] = *reinterpret_cast<short8*>(ll);
            }
        }

#pragma unroll 1
        for (int res = 0; res < 8; ++res) {
            const int S   = res & 3;
            const int off = (res >> 2) << 2;          // 0 or 4 cols
            const unsigned short* hb = &xh[S][0][0] + off;
            const unsigned short* lb = &xl[S][0][0] + off;

            f32x4 acc = {0.f, 0.f, 0.f, 0.f};
#pragma unroll
            for (int kk = 0; kk < 8; ++kk) {
                short8 ah, al;
                if (off == 0) {                       // 16B-aligned: b128
                    ah = *reinterpret_cast<const short8*>(hb + preidx[kk]);
                    al = *reinterpret_cast<const short8*>(lb + preidx[kk]);
                } else {                              // 8B-aligned: 2x b64
                    short4v h0 = *reinterpret_cast<const short4v*>(hb + preidx[kk]);
                    short4v h1 = *reinterpret_cast<const short4v*>(hb + preidx[kk] + 4);
                    short4v l0 = *reinterpret_cast<const short4v*>(lb + preidx[kk]);
                    short4v l1 = *reinterpret_cast<const short4v*>(lb + preidx[kk] + 4);
                    ah = __builtin_shufflevector(h0, h1, 0, 1, 2, 3, 4, 5, 6, 7);
                    al = __builtin_shufflevector(l0, l1, 0, 1, 2, 3, 4, 5, 6, 7);
                }
                acc = __builtin_amdgcn_mfma_f32_16x16x32_bf16(ah, wh[kk], acc, 0, 0, 0);
                acc = __builtin_amdgcn_mfma_f32_16x16x32_bf16(al, wh[kk], acc, 0, 0, 0);
                acc = __builtin_amdgcn_mfma_f32_16x16x32_bf16(ah, wl[kk], acc, 0, 0, 0);
            }

            // ---- epilogue: repair borderline, set pool bits ----
#pragma unroll
            for (int reg = 0; reg < 4; ++reg) {
                float v = acc[reg];
                const int m   = q * 4 + reg;
                const int pcg = w0 + res + 8 * m;     // global pot col
                const bool valid = (fm < FM) && (pcg <= 2007);
                if (valid && __builtin_fabsf(v - THRESH) < MARGIN) {
                    float pot = 0.f;
#pragma unroll 1
                    for (int r2 = 0; r2 < 6; ++r2) {
                        const float* xr = x + ((size_t)tt * H_ + rowbase + j_p + r2) * WD_ + pcg;
                        const float* wr = Wg + (size_t)sec * FM * 240 + (size_t)fm * 240 + r2 * 40;
#pragma unroll 1
                        for (int c = 0; c < 40; ++c)
                            pot = fmaf(xr[c], wr[c], pot);
                    }
                    v = pot;
                }
                if (v > THRESH)
                    mask |= 1u << (reg * 8 + ft * 2 + (res >> 2));
            }
        }
    }

    lmask[j_p][L] = mask;
    __syncthreads();

    // ---- cross-wave OR + pooled write: 64 fm x 32 pooled cols ----
    for (int e = tid; e < 2048; e += 256) {
        const int fmo = e >> 5, p = e & 31;
        const int m = p >> 1, rg = p & 1, ftc = fmo >> 4, fn = fmo & 15;
        const int lane = (m >> 2) * 16 + fn;
        const int bitpos = (m & 3) * 8 + ftc * 2 + rg;
        const unsigned bits = lmask[0][lane] | lmask[1][lane] |
                              lmask[2][lane] | lmask[3][lane];
        const int pg = coltile * 32 + p;
        if (fmo < FM && pg < WP)
            out[((size_t)(sec * T_ + tt) * FM + fmo) * WP + pg] =
                ((bits >> bitpos) & 1u) ? 1.0f : 0.0f;
    }
}

// ---------------- init (fallback only) ----------------
__global__ void init_kernel(int* __restrict__ ws)
{
    if (threadIdx.x < NSEC) ws[threadIdx.x] = 0x7fffffff;
}

// ---------------- Kernel C: first-spike scan + argmin reduce ----------------
__global__ __launch_bounds__(256) void scan_kernel(
    const float* __restrict__ pooled, int* __restrict__ ws)
{
    __shared__ int sk[256];
    const int sec = blockIdx.x / 99;
    const int bi  = blockIdx.x % 99;
    const int e   = bi * 256 + threadIdx.x;
    int key = 0x7fffffff;
    if (e < FM * WP) {
        const int fm = e / WP;
        const int wp = e % WP;
        const size_t base = ((size_t)(sec * T_) * FM + fm) * WP + wp;
        const size_t tstride = (size_t)FM * WP;
#pragma unroll 1
        for (int t = 0; t < T_; ++t) {
            if (pooled[base + t * tstride] > 0.f) { key = (t << 15) | e; break; }
        }
    }
    sk[threadIdx.x] = key;
    __syncthreads();
    for (int s = 128; s > 0; s >>= 1) {
        if (threadIdx.x < s) sk[threadIdx.x] = min(sk[threadIdx.x], sk[threadIdx.x + s]);
        __syncthreads();
    }
    if (threadIdx.x == 0) atomicMin(&ws[sec], sk[0]);
}

// ---------------- Kernel D: finalize winners ----------------
__global__ void finalize_kernel(const int* __restrict__ ws, float* __restrict__ out)
{
    const int i = threadIdx.x;
    if (i < NSEC) {
        const int key = ws[i];
        float feat;
        if (key == 0x7fffffff) feat = -1.0f;
        else                   feat = (float)((key & 32767) / WP);
        out[POOLED_SIZE + i] = feat;
    }
}

extern "C" void kernel_launch(void* const* d_in, const int* in_sizes, int n_in,
                              void* d_out, int out_size, void* d_ws, size_t ws_size,
                              hipStream_t stream) {
    const float* x  = (const float*)d_in[0];
    const float* Wg = (const float*)d_in[1];
    float* out = (float*)d_out;
    int*   wsi = (int*)d_ws;
    uint4* wfh = (uint4*)((char*)d_ws + 256);
    uint4* wfl = wfh + NFRAG;

    const bool pre = ws_size >= 256 + (size_t)NFRAG * 16 * 2;   // 590 KB
    if (pre) {
        prep_kernel<<<dim3(72), dim3(256), 0, stream>>>(Wg, wsi, wfh, wfl);
        conv_pool_kernel<true><<<dim3(4320), dim3(256), 0, stream>>>(x, Wg, wfh, wfl, out);
    } else {
        init_kernel<<<dim3(1), dim3(64), 0, stream>>>(wsi);
        conv_pool_kernel<false><<<dim3(4320), dim3(256), 0, stream>>>(x, Wg, wfh, wfl, out);
    }
    scan_kernel<<<dim3(NSEC * 99), dim3(256), 0, stream>>>(out, wsi);
    finalize_kernel<<<dim3(1), dim3(16), 0, stream>>>(wsi, out);
}